// Round 5
// baseline (7501.945 us; speedup 1.0000x reference)
//
#include <hip/hip_runtime.h>
#include <hip/hip_bf16.h>

// ---------------------------------------------------------------------------
// UnifiedModelRNN: B=256,S=512,I=64,H=256. 16 blocks x 512 threads (8 waves),
// 1 block/CU; block g owns batch rows [16g,16g+16). No grid sync.
// R5: lgkmcnt-only barriers (loads survive barriers), amdgpu_waves_per_eu(2,2)
// for a 256-VGPR budget, gate kts{4,5} register-resident, kts{2,3,6,7,8,0,1}
// streamed via two rotating 8-frag buffers issued >=1 phase early, shared
// h-fragments for heads + gates.
// ---------------------------------------------------------------------------

typedef float f32x4 __attribute__((ext_vector_type(4)));
typedef short s16x8 __attribute__((ext_vector_type(8)));

#define S_LEN 512
#define I_DIM 64
#define K_DIM 320
#define NT    512

#define WS_GF    0
#define WS_PF    327680
#define WS_TF    344064
#define WS_AXF   360448
#define WS_A2F   364544
#define WS_TOTAL 368640

#define OUT_PIT  0
#define OUT_TIME 131072
#define OUT_AR   262144

#define ALD 328
#define XLD 72

__device__ __forceinline__ float sigf(float x) {
  return 1.0f / (1.0f + __expf(-x));
}
__device__ __forceinline__ float tanh_fast(float x) {
  float c = fminf(fmaxf(x, -15.0f), 15.0f);
  float e = __expf(2.0f * c);
  return (e - 1.0f) / (e + 1.0f);
}
__device__ __forceinline__ unsigned short f2bf(float f) {
  __hip_bfloat16 h = __float2bfloat16(f);
  return *reinterpret_cast<unsigned short*>(&h);
}
// LDS-only barrier: does NOT drain vmcnt -> global loads stay in flight.
__device__ __forceinline__ void sync_lds() {
  asm volatile("s_waitcnt lgkmcnt(0)" ::: "memory");
  __builtin_amdgcn_s_barrier();
  asm volatile("" ::: "memory");
}

__global__ void prep_kernel(const float* __restrict__ w_ih,
                            const float* __restrict__ w_hh,
                            const float* __restrict__ pit_w1,
                            const float* __restrict__ time_w1,
                            const float* __restrict__ ar_w1,
                            const float* __restrict__ ar_w2,
                            unsigned short* __restrict__ ws) {
  int idx = blockIdx.x * 256 + threadIdx.x;
  if (idx >= WS_TOTAL) return;
  int lane = (idx >> 3) & 63;
  int e    = idx & 7;
  int lrow = lane & 15, lgrp = lane >> 4;
  float v;
  if (idx < WS_PF) {
    int f = idx >> 9;
    int w = f / 80, r = f - w * 80;
    int qm = r / 10, kt = r - qm * 10;
    int q = qm >> 1, m = qm & 1;
    int row = q * 256 + w * 32 + m * 16 + lrow;
    int col = kt * 32 + lgrp * 8 + e;
    v = (col < I_DIM) ? w_ih[row * I_DIM + col] : w_hh[row * 256 + col - I_DIM];
  } else if (idx < WS_TF) {
    int f = (idx - WS_PF) >> 9;
    int wv = f >> 3, kt = f & 7;
    v = pit_w1[(wv * 16 + lrow) * 256 + kt * 32 + lgrp * 8 + e];
  } else if (idx < WS_AXF) {
    int f = (idx - WS_TF) >> 9;
    int wv = f >> 3, kt = f & 7;
    v = time_w1[(wv * 16 + lrow) * 257 + kt * 32 + lgrp * 8 + e];
  } else if (idx < WS_A2F) {
    int f = (idx - WS_AXF) >> 9;
    int wv = f >> 1, kt = f & 1;
    v = ar_w1[(wv * 16 + lrow) * 66 + 2 + kt * 32 + lgrp * 8 + e];
  } else {
    int f = (idx - WS_A2F) >> 9;
    int wv = f >> 1, kt = f & 1;
    v = ar_w2[(wv * 16 + lrow) * 64 + kt * 32 + lgrp * 8 + e];
  }
  ws[idx] = f2bf(v);
}

#define AFRAG(kt) (*(const s16x8*)&A_lds[lrow][(kt) * 32 + 8 * lgrp])
#define GFRAG(kt, qm) (*(const s16x8*)&ws[((wave * 80 + (qm) * 10 + (kt)) * 64 + lane) * 8])
#define GBUNDLE(af, barr)                                                        \
  _Pragma("unroll") for (int qm = 0; qm < 8; ++qm)                               \
      acc2[qm] = __builtin_amdgcn_mfma_f32_16x16x32_bf16((af), (barr)[qm],       \
                                                         acc2[qm], 0, 0, 0);

__global__ __launch_bounds__(NT)
__attribute__((amdgpu_waves_per_eu(2, 2)))
void rnn_kernel(
    const float* __restrict__ x,
    const float* __restrict__ b_ih, const float* __restrict__ b_hh,
    const float* __restrict__ pit_b1, const float* __restrict__ pit_w2,
    const float* __restrict__ pit_b2,
    const float* __restrict__ time_w1, const float* __restrict__ time_b1,
    const float* __restrict__ time_w2, const float* __restrict__ time_b2,
    const float* __restrict__ ar_w1, const float* __restrict__ ar_b1,
    const float* __restrict__ ar_b2,
    const unsigned short* __restrict__ ws,
    float* __restrict__ out)
{
  __shared__ __align__(16) unsigned short A_lds[16][ALD];
  __shared__ __align__(16) unsigned short xo_lds[16][XLD];
  __shared__ __align__(16) unsigned short ar1_lds[16][XLD];
  __shared__ __align__(16) unsigned short g9_lds[64 * 512];
  __shared__ __align__(16) unsigned short pit_lds[32 * 512];
  __shared__ __align__(16) unsigned short tim_lds[32 * 512];
  __shared__ float pitp[4][16];
  __shared__ float timep[4][16];

  const int tid  = threadIdx.x;
  const int wave = tid >> 6;
  const int lane = tid & 63;
  const int lrow = lane & 15;
  const int lgrp = lane >> 4;
  const int b0   = blockIdx.x * 16;
  const int hcol = (wave & 3) * 16 + lrow;

  for (int c = tid; c < 4096; c += NT) {
    int f = c >> 6, lc = c & 63;
    int fws = (f >> 3) * 80 + (f & 7) * 10 + 9;
    *(s16x8*)&g9_lds[c * 8] = *(const s16x8*)&ws[(fws * 64 + lc) * 8];
  }
  for (int c = tid; c < 2048; c += NT) {
    *(s16x8*)&pit_lds[c * 8] = *(const s16x8*)&ws[WS_PF + c * 8];
    *(s16x8*)&tim_lds[c * 8] = *(const s16x8*)&ws[WS_TF + c * 8];
  }
  for (int i = tid; i < 16 * ALD; i += NT) (&A_lds[0][0])[i] = 0;

  // register-resident gate weights: kts {4,5}
  s16x8 wreg4[8], wreg5[8];
#pragma unroll
  for (int qm = 0; qm < 8; ++qm) wreg4[qm] = GFRAG(4, qm);
#pragma unroll
  for (int qm = 0; qm < 8; ++qm) wreg5[qm] = GFRAG(5, qm);

  float gbias[8];
#pragma unroll
  for (int qm = 0; qm < 8; ++qm) {
    int g = (qm >> 1) * 256 + wave * 32 + (qm & 1) * 16 + lrow;
    gbias[qm] = b_ih[g] + b_hh[g];
  }

  s16x8 arw[2];
  float pb1v = 0, pw2v = 0, tb1v = 0, tw2v = 0, twlv = 0;
  float ab1v = 0, arpv = 0, artv = 0, ab2v = 0;
  if (wave < 4) {
    arw[0] = *(const s16x8*)&ws[WS_AXF + (((wave & 3) * 2 + 0) * 64 + lane) * 8];
    arw[1] = *(const s16x8*)&ws[WS_AXF + (((wave & 3) * 2 + 1) * 64 + lane) * 8];
    pb1v = pit_b1[hcol]; pw2v = pit_w2[hcol];
    ab1v = ar_b1[hcol];  arpv = ar_w1[hcol * 66]; artv = ar_w1[hcol * 66 + 1];
  } else {
    arw[0] = *(const s16x8*)&ws[WS_A2F + (((wave & 3) * 2 + 0) * 64 + lane) * 8];
    arw[1] = *(const s16x8*)&ws[WS_A2F + (((wave & 3) * 2 + 1) * 64 + lane) * 8];
    tb1v = time_b1[hcol]; tw2v = time_w2[hcol];
    twlv = time_w1[hcol * 257 + 256]; ab2v = ar_b2[hcol];
  }
  const float pb2 = pit_b2[0], tb2 = time_b2[0];

  const int srow = tid >> 5;
  const int sc2  = (tid & 31) * 2;
  const size_t xbase = (size_t)(b0 + srow) * S_LEN * I_DIM + sc2;
  float2 xpre = *reinterpret_cast<const float2*>(&x[xbase]);
  __syncthreads();
  A_lds[srow][sc2]     = f2bf(xpre.x);
  A_lds[srow][sc2 + 1] = f2bf(xpre.y);
  *reinterpret_cast<float2*>(&out[OUT_AR + xbase]) = xpre;

  float cst[2][4];
#pragma unroll
  for (int m = 0; m < 2; ++m)
#pragma unroll
    for (int r = 0; r < 4; ++r) cst[m][r] = 0.0f;
  __syncthreads();

  // prologue: full gates(0)
  f32x4 acc2[8];
#pragma unroll
  for (int qm = 0; qm < 8; ++qm) {
    f32x4 tv; tv[0] = tv[1] = tv[2] = tv[3] = gbias[qm];
    acc2[qm] = tv;
  }
#pragma unroll
  for (int kt = 0; kt < 10; ++kt) {
    s16x8 aK = AFRAG(kt);
#pragma unroll
    for (int qm = 0; qm < 8; ++qm)
      acc2[qm] = __builtin_amdgcn_mfma_f32_16x16x32_bf16(aK, GFRAG(kt, qm), acc2[qm], 0, 0, 0);
  }

  // =========================== time loop ===========================
  for (int t = 0; t < S_LEN; ++t) {
    // early-issue streamed gate frags kt2,kt3 (land during LSTM/sync_a)
    s16x8 bldA[8], bldB[8];
#pragma unroll
    for (int qm = 0; qm < 8; ++qm) bldA[qm] = GFRAG(2, qm);
#pragma unroll
    for (int qm = 0; qm < 8; ++qm) bldB[qm] = GFRAG(3, qm);

    xo_lds[srow][sc2]     = f2bf(xpre.x);
    xo_lds[srow][sc2 + 1] = f2bf(xpre.y);
    if (t + 1 < S_LEN)
      xpre = *reinterpret_cast<const float2*>(&x[xbase + (size_t)(t + 1) * I_DIM]);

    // LSTM (c in regs) -> h into A_lds
#pragma unroll
    for (int m = 0; m < 2; ++m)
#pragma unroll
      for (int r = 0; r < 4; ++r) {
        float ig = sigf(acc2[0 + m][r]);
        float fg = sigf(acc2[2 + m][r]);
        float gg = tanh_fast(acc2[4 + m][r]);
        float og = sigf(acc2[6 + m][r]);
        float c  = fg * cst[m][r] + ig * gg;
        cst[m][r] = c;
        A_lds[lgrp * 4 + r][64 + wave * 32 + m * 16 + lrow] = f2bf(og * tanh_fast(c));
      }
#pragma unroll
    for (int qm = 0; qm < 8; ++qm) {
      f32x4 tv; tv[0] = tv[1] = tv[2] = tv[3] = gbias[qm];
      acc2[qm] = tv;
    }
    sync_lds();  // sync_a

    s16x8 hfr[8];
#pragma unroll
    for (int kt = 0; kt < 8; ++kt)
      hfr[kt] = *(const s16x8*)&A_lds[lrow][64 + kt * 32 + 8 * lgrp];

    // ---- P1 ----
    GBUNDLE(hfr[0], bldA);             // kt2
#pragma unroll
    for (int qm = 0; qm < 8; ++qm) bldA[qm] = GFRAG(6, qm);
    GBUNDLE(hfr[1], bldB);             // kt3
#pragma unroll
    for (int qm = 0; qm < 8; ++qm) bldB[qm] = GFRAG(7, qm);
    GBUNDLE(hfr[2], wreg4);            // kt4
    GBUNDLE(hfr[3], wreg5);            // kt5
    {
#pragma unroll
      for (int qm = 0; qm < 8; ++qm) {
        s16x8 bK = *(const s16x8*)&g9_lds[((wave * 8 + qm) * 64 + lane) * 8];
        acc2[qm] = __builtin_amdgcn_mfma_f32_16x16x32_bf16(hfr[7], bK, acc2[qm], 0, 0, 0);
      }
    }
    f32x4 hacc;
    {
      float hb = (wave < 4) ? pb1v : tb1v;
      hacc[0] = hacc[1] = hacc[2] = hacc[3] = hb;
      const unsigned short* hbp = (wave < 4) ? pit_lds : tim_lds;
#pragma unroll
      for (int kt = 0; kt < 8; ++kt) {
        s16x8 bH = *(const s16x8*)&hbp[(((wave & 3) * 8 + kt) * 64 + lane) * 8];
        hacc = __builtin_amdgcn_mfma_f32_16x16x32_bf16(hfr[kt], bH, hacc, 0, 0, 0);
      }
    }
    if (wave < 4) {
      float v[4];
#pragma unroll
      for (int r = 0; r < 4; ++r) v[r] = fmaxf(hacc[r], 0.0f) * pw2v;
#pragma unroll
      for (int off = 1; off < 16; off <<= 1)
#pragma unroll
        for (int r = 0; r < 4; ++r) v[r] += __shfl_xor(v[r], off);
      if (lrow == 0) {
#pragma unroll
        for (int r = 0; r < 4; ++r) pitp[wave][lgrp * 4 + r] = v[r];
      }
    }
    sync_lds();  // sync_c

    // ---- P2 ----
    GBUNDLE(hfr[4], bldA);             // kt6
#pragma unroll
    for (int qm = 0; qm < 8; ++qm) bldA[qm] = GFRAG(8, qm);

    f32x4 aracc;
    if (wave < 4) {
      aracc[0] = aracc[1] = aracc[2] = aracc[3] = ab1v;
#pragma unroll
      for (int kt = 0; kt < 2; ++kt) {
        s16x8 aX = *(const s16x8*)&xo_lds[lrow][kt * 32 + 8 * lgrp];
        aracc = __builtin_amdgcn_mfma_f32_16x16x32_bf16(aX, arw[kt], aracc, 0, 0, 0);
      }
      if (wave == 0 && lane < 16) {
        float pvs = pitp[0][lane] + pitp[1][lane] + pitp[2][lane] + pitp[3][lane] + pb2;
        out[OUT_PIT + (size_t)(b0 + lane) * S_LEN + t] = pvs;
      }
    } else {
      float v[4];
#pragma unroll
      for (int r = 0; r < 4; ++r) {
        int row = lgrp * 4 + r;
        float pvr = pitp[0][row] + pitp[1][row] + pitp[2][row] + pitp[3][row] + pb2;
        v[r] = fmaxf(hacc[r] + pvr * twlv, 0.0f) * tw2v;
      }
#pragma unroll
      for (int off = 1; off < 16; off <<= 1)
#pragma unroll
        for (int r = 0; r < 4; ++r) v[r] += __shfl_xor(v[r], off);
      if (lrow == 0) {
#pragma unroll
        for (int r = 0; r < 4; ++r) timep[wave & 3][lgrp * 4 + r] = v[r];
      }
    }
    sync_lds();  // sync_d

    // ---- P3 ----
    GBUNDLE(hfr[5], bldB);             // kt7
#pragma unroll
    for (int qm = 0; qm < 8; ++qm) bldB[qm] = GFRAG(0, qm);

    if (wave < 4) {
#pragma unroll
      for (int r = 0; r < 4; ++r) {
        int row = lgrp * 4 + r;
        float pvr = pitp[0][row] + pitp[1][row] + pitp[2][row] + pitp[3][row] + pb2;
        float tvr = timep[0][row] + timep[1][row] + timep[2][row] + timep[3][row] + tb2;
        float a1 = aracc[r] + pvr * arpv + tvr * artv;
        ar1_lds[row][hcol] = f2bf(fmaxf(a1, 0.0f));
      }
    } else if (wave == 4 && lane < 16) {
      float tvs = timep[0][lane] + timep[1][lane] + timep[2][lane] + timep[3][lane] + tb2;
      out[OUT_TIME + (size_t)(b0 + lane) * S_LEN + t] = tvs;
    }
    sync_lds();  // sync_e

    // ---- P4 ----
    GBUNDLE(hfr[6], bldA);             // kt8
#pragma unroll
    for (int qm = 0; qm < 8; ++qm) bldA[qm] = GFRAG(1, qm);

    if (wave >= 4) {
      f32x4 nacc;
      nacc[0] = nacc[1] = nacc[2] = nacc[3] = ab2v;
#pragma unroll
      for (int kt = 0; kt < 2; ++kt) {
        s16x8 aR = *(const s16x8*)&ar1_lds[lrow][kt * 32 + 8 * lgrp];
        nacc = __builtin_amdgcn_mfma_f32_16x16x32_bf16(aR, arw[kt], nacc, 0, 0, 0);
      }
#pragma unroll
      for (int r = 0; r < 4; ++r) {
        int row = lgrp * 4 + r;
        A_lds[row][hcol] = f2bf(nacc[r]);
        if (t < S_LEN - 1)
          out[OUT_AR + (size_t)(b0 + row) * S_LEN * I_DIM + (size_t)(t + 1) * I_DIM + hcol] = nacc[r];
      }
    }
    sync_lds();  // sync_f

    // ---- P5: gates-x ----
    {
      s16x8 a0 = AFRAG(0);
      GBUNDLE(a0, bldB);               // kt0
      s16x8 a1 = AFRAG(1);
      GBUNDLE(a1, bldA);               // kt1
    }
  }
}

extern "C" void kernel_launch(void* const* d_in, const int* in_sizes, int n_in,
                              void* d_out, int out_size, void* d_ws, size_t ws_size,
                              hipStream_t stream) {
  const float* x       = (const float*)d_in[0];
  const float* w_ih    = (const float*)d_in[1];
  const float* w_hh    = (const float*)d_in[2];
  const float* b_ih    = (const float*)d_in[3];
  const float* b_hh    = (const float*)d_in[4];
  const float* pit_w1  = (const float*)d_in[5];
  const float* pit_b1  = (const float*)d_in[6];
  const float* pit_w2  = (const float*)d_in[7];
  const float* pit_b2  = (const float*)d_in[8];
  const float* time_w1 = (const float*)d_in[9];
  const float* time_b1 = (const float*)d_in[10];
  const float* time_w2 = (const float*)d_in[11];
  const float* time_b2 = (const float*)d_in[12];
  const float* ar_w1   = (const float*)d_in[13];
  const float* ar_b1   = (const float*)d_in[14];
  const float* ar_w2   = (const float*)d_in[15];
  const float* ar_b2   = (const float*)d_in[16];
  unsigned short* ws   = (unsigned short*)d_ws;
  float* out           = (float*)d_out;

  prep_kernel<<<dim3((WS_TOTAL + 255) / 256), dim3(256), 0, stream>>>(
      w_ih, w_hh, pit_w1, time_w1, ar_w1, ar_w2, ws);
  rnn_kernel<<<dim3(16), dim3(NT), 0, stream>>>(
      x, b_ih, b_hh, pit_b1, pit_w2, pit_b2,
      time_w1, time_b1, time_w2, time_b2,
      ar_w1, ar_b1, ar_b2, ws, out);
}